// Round 7
// baseline (255.270 us; speedup 1.0000x reference)
//
#include <hip/hip_runtime.h>
#include <stdint.h>

typedef unsigned short u16;
typedef __attribute__((ext_vector_type(8))) short bf16x8;
typedef __attribute__((ext_vector_type(4))) float f32x4;

#define NB 32
#define CH 512
#define HP 30
#define KTOT 4608         // 9*512
#define BM 256
#define BN 224
#define BK 64
#define ABYTES 32768      // BM*BK*2
#define BBYTES 28672      // BN*BK*2
#define BUFU16 30720      // (ABYTES+BBYTES)/2
#define KSTEPS 72         // 4608/64

__device__ __forceinline__ u16 f2bf(float f) {
    uint32_t u = __float_as_uint(f);
    uint32_t r = (u + 0x7fffu + ((u >> 16) & 1u)) >> 16;
    return (u16)r;
}

// ---------------- kernel 1: per-(b,c) centroid stats (proven) ----
__global__ __launch_bounds__(256) void stats_kernel(
    const float* __restrict__ x, float* __restrict__ muX, float* __restrict__ muY)
{
    int pair = blockIdx.x * 4 + (threadIdx.x >> 6);   // b*512 + c
    int lane = threadIdx.x & 63;
    const float* xp = x + (size_t)pair * 784;
    float s = 0.f, sx = 0.f, sy = 0.f;
    for (int e = lane; e < 784; e += 64) {
        float v = xp[e];
        int i = e / 28, j = e - i * 28;
        s += v;
        sx += (float)(i + 1) * v;
        sy += (float)(j + 1) * v;
    }
    #pragma unroll
    for (int off = 32; off > 0; off >>= 1) {
        s  += __shfl_down(s, off);
        sx += __shfl_down(sx, off);
        sy += __shfl_down(sy, off);
    }
    if (lane == 0) {
        float S = fmaxf(s, 1e-9f);
        float mx = fmaxf(rintf(sx / S), 1.0f);
        float my = fmaxf(rintf(sy / S), 1.0f);
        int ix = (int)(mx - 1.0f); if (ix > 27) ix = 27;
        int iy = (int)(my - 1.0f); if (iy > 27) iy = 27;
        muX[pair] = -1.0f + (2.0f / 27.0f) * (float)ix;
        muY[pair] = -1.0f + (2.0f / 27.0f) * (float)iy;
    }
}

// ------- kernel 2: mask+relu transpose (proven) ----------
#define TSTR 520
__global__ __launch_bounds__(256) void mask_relu_transpose(
    const float* __restrict__ x, const float* __restrict__ mw,
    const float* __restrict__ filt, const float* __restrict__ muX,
    const float* __restrict__ muY, u16* __restrict__ xr_pad)
{
    __shared__ u16 tile[28 * TSTR];   // [j][c]
    int bid = blockIdx.x;
    int b = bid / 28, i = bid - (bid / 28) * 28;
    int tid = threadIdx.x;
    float px = -1.0f + (2.0f / 27.0f) * (float)i;
    const float* xb = x + (size_t)b * CH * 784 + i * 28;
    const float* muXb = muX + b * CH;
    const float* muYb = muY + b * CH;
    #pragma unroll 8
    for (int k = 0; k < 56; ++k) {
        int e = tid + k * 256;          // e = c*28 + j  (coalesced global read)
        int c = e / 28, j = e - c * 28;
        float v = xb[c * 784 + j];
        float py = -1.0f + (2.0f / 27.0f) * (float)j;
        float m = 1.0f - (fabsf(px - muXb[c]) + fabsf(py - muYb[c])) * mw[c];
        m = fmaxf(m, -1.0f);
        if (filt[c] != 1.0f) m = 1.0f;
        tile[j * TSTR + c] = f2bf(fmaxf(v * m, 0.0f));
    }
    __syncthreads();
    u16* outb = xr_pad + (((size_t)b * HP + (i + 1)) * HP + 1) * CH;
    #pragma unroll
    for (int k = 0; k < 7; ++k) {
        int ch = tid + k * 256;
        int j = ch >> 6;
        int c0 = (ch & 63) << 3;
        *reinterpret_cast<uint4*>(outb + (size_t)j * CH + c0) =
            *reinterpret_cast<const uint4*>(&tile[j * TSTR + c0]);
    }
}

// ------- kernel 3: weight reorder (proven) ----------
__global__ __launch_bounds__(256) void weight_reorder(
    const float* __restrict__ w, u16* __restrict__ w_r)
{
    __shared__ u16 t[KTOT];
    int oc = blockIdx.x;
    const float* wrow = w + (size_t)oc * KTOT;
    int tid = threadIdx.x;
    #pragma unroll
    for (int k = 0; k < 18; ++k) {
        int idx = tid + k * 256;
        int ic = idx / 9, tap = idx - ic * 9;
        t[tap * 512 + ic] = f2bf(wrow[idx]);
    }
    __syncthreads();
    u16* dst = w_r + (size_t)oc * KTOT;
    #pragma unroll
    for (int k = 0; k < 3; ++k) {
        int ch = tid + k * 256;
        if (ch < 576)
            *reinterpret_cast<uint4*>(dst + ch * 8) =
                *reinterpret_cast<const uint4*>(&t[ch * 8]);
    }
}

// ------- kernel 4: implicit-GEMM conv, 4-phase schedule (T3+T4+T5) -------
// 224 blocks, 512 threads = 8 waves (4m x 2n), wave tile 64x112
__global__ __launch_bounds__(512, 2) void conv_gemm(
    const u16* __restrict__ w_r, const u16* __restrict__ xr_pad,
    const float* __restrict__ bias, float* __restrict__ out)
{
    __shared__ __align__(16) u16 smem[2][BUFU16];      // 120 KiB
    int p = blockIdx.x;
    int bid = (p & 7) * 28 + (p >> 3);     // XCD x -> bids [28x, 28x+28)
    int mt = bid / 112, nt = bid - mt * 112;
    int m0 = mt * 256;
    int n0 = nt * 224;
    int tid = threadIdx.x;
    int lane = tid & 63;
    int w = tid >> 6;
    int wm = w >> 1, wn = w & 1;

    // staging addresses; swizzle baked into GLOBAL source column, LDS dest linear
    uint32_t aoff[4], boff[4], ldsA[4], ldsB[4];
    bool bmask[4];
    #pragma unroll
    for (int it = 0; it < 4; ++it) {
        int c = tid * 16 + it * 8192;             // byte offset in tile
        int row = c >> 7;                          // 128B rows
        int scol = (c & 127) ^ ((row & 7) << 4);
        aoff[it] = (uint32_t)(m0 + row) * KTOT + (scol >> 1);
        ldsA[it] = c >> 1;
        bmask[it] = (c < BBYTES);                  // wave-uniform
        int rb = (row < BN) ? row : 0;
        int n = n0 + rb;
        int b2 = n / 784, s2 = n - b2 * 784;
        int oh = s2 / 28, ow = s2 - oh * 28;
        boff[it] = (uint32_t)(((b2 * HP + oh) * HP + ow) * CH) + (scol >> 1);
        ldsB[it] = (uint32_t)((c < BBYTES ? c : 0) >> 1);
    }

    auto stageA = [&](int buf, int ks) {
        u16* sA = smem[buf];
        int koff = ks * 64;
        #pragma unroll
        for (int it = 0; it < 4; ++it) {
            __builtin_amdgcn_global_load_lds(
                (const __attribute__((address_space(1))) uint32_t*)(w_r + aoff[it] + koff),
                (__attribute__((address_space(3))) uint32_t*)(sA + ldsA[it]),
                16, 0, 0);
        }
    };
    auto stageB = [&](int buf, int ks) {
        u16* sB = smem[buf] + (ABYTES >> 1);
        int tap = ks >> 3;
        int kh = tap / 3, kw = tap - kh * 3;
        int xoff = (kh * HP + kw) * CH + (ks & 7) * 64;
        #pragma unroll
        for (int it = 0; it < 4; ++it) {
            if (bmask[it]) {
                __builtin_amdgcn_global_load_lds(
                    (const __attribute__((address_space(1))) uint32_t*)(xr_pad + boff[it] + xoff),
                    (__attribute__((address_space(3))) uint32_t*)(sB + ldsB[it]),
                    16, 0, 0);
            }
        }
    };

    f32x4 acc[4][7];
    #pragma unroll
    for (int m = 0; m < 4; ++m)
        #pragma unroll
        for (int ni = 0; ni < 7; ++ni)
            acc[m][ni] = (f32x4){0.f, 0.f, 0.f, 0.f};

    int r15 = lane & 15;
    int rq = lane >> 4;
    int xorv = (r15 & 7) << 4;
    int cb0 = ((rq * 16) ^ xorv) >> 1;        // kk=0 swizzled column (u16)
    int cb1 = ((rq * 16 + 64) ^ xorv) >> 1;   // kk=1
    int arow = (wm * 64 + r15) * 64;          // + m*1024
    int brow = (ABYTES >> 1) + (wn * 112 + r15) * 64;   // + ni*1024

    stageA(0, 0);
    stageB(0, 0);
    __syncthreads();                           // prologue: full drain, buf0 ready

    for (int ks = 0; ks < KSTEPS; ++ks) {
        const u16* sm = smem[ks & 1];
        const int nbuf = (ks + 1) & 1;
        const bool pf = (ks + 1 < KSTEPS);

        // ---- P1: stage A(ks+1) | ds_read kk0 a0..3,b0..3 | 16 MFMA ----
        if (pf) stageA(nbuf, ks + 1);
        bf16x8 a0[4], bA[4];
        #pragma unroll
        for (int m = 0; m < 4; ++m)
            a0[m] = *reinterpret_cast<const bf16x8*>(sm + arow + m * 1024 + cb0);
        #pragma unroll
        for (int ni = 0; ni < 4; ++ni)
            bA[ni] = *reinterpret_cast<const bf16x8*>(sm + brow + ni * 1024 + cb0);
        __builtin_amdgcn_s_barrier();
        asm volatile("s_waitcnt lgkmcnt(0)" ::: "memory");
        __builtin_amdgcn_sched_barrier(0);
        __builtin_amdgcn_s_setprio(1);
        #pragma unroll
        for (int ni = 0; ni < 4; ++ni)
            #pragma unroll
            for (int m = 0; m < 4; ++m)
                acc[m][ni] = __builtin_amdgcn_mfma_f32_16x16x32_bf16(a0[m], bA[ni], acc[m][ni], 0, 0, 0);
        __builtin_amdgcn_s_setprio(0);
        __builtin_amdgcn_s_barrier();

        // ---- P2: stage B(ks+1) | ds_read kk0 b4..6 | 12 MFMA ----
        if (pf) stageB(nbuf, ks + 1);
        bf16x8 bB[3];
        #pragma unroll
        for (int ni = 0; ni < 3; ++ni)
            bB[ni] = *reinterpret_cast<const bf16x8*>(sm + brow + (ni + 4) * 1024 + cb0);
        __builtin_amdgcn_s_barrier();
        asm volatile("s_waitcnt lgkmcnt(0)" ::: "memory");
        __builtin_amdgcn_sched_barrier(0);
        __builtin_amdgcn_s_setprio(1);
        #pragma unroll
        for (int ni = 0; ni < 3; ++ni)
            #pragma unroll
            for (int m = 0; m < 4; ++m)
                acc[m][ni + 4] = __builtin_amdgcn_mfma_f32_16x16x32_bf16(a0[m], bB[ni], acc[m][ni + 4], 0, 0, 0);
        __builtin_amdgcn_s_setprio(0);
        __builtin_amdgcn_s_barrier();

        // ---- P3: ds_read kk1 a0..3,b0..3 | 16 MFMA ----
        bf16x8 a1[4], bC[4];
        #pragma unroll
        for (int m = 0; m < 4; ++m)
            a1[m] = *reinterpret_cast<const bf16x8*>(sm + arow + m * 1024 + cb1);
        #pragma unroll
        for (int ni = 0; ni < 4; ++ni)
            bC[ni] = *reinterpret_cast<const bf16x8*>(sm + brow + ni * 1024 + cb1);
        __builtin_amdgcn_s_barrier();
        asm volatile("s_waitcnt lgkmcnt(0)" ::: "memory");
        __builtin_amdgcn_sched_barrier(0);
        __builtin_amdgcn_s_setprio(1);
        #pragma unroll
        for (int ni = 0; ni < 4; ++ni)
            #pragma unroll
            for (int m = 0; m < 4; ++m)
                acc[m][ni] = __builtin_amdgcn_mfma_f32_16x16x32_bf16(a1[m], bC[ni], acc[m][ni], 0, 0, 0);
        __builtin_amdgcn_s_setprio(0);
        __builtin_amdgcn_s_barrier();

        // ---- P4: ds_read kk1 b4..6 | 12 MFMA | vmcnt(0) handoff ----
        bf16x8 bD[3];
        #pragma unroll
        for (int ni = 0; ni < 3; ++ni)
            bD[ni] = *reinterpret_cast<const bf16x8*>(sm + brow + (ni + 4) * 1024 + cb1);
        __builtin_amdgcn_s_barrier();
        asm volatile("s_waitcnt lgkmcnt(0)" ::: "memory");
        __builtin_amdgcn_sched_barrier(0);
        __builtin_amdgcn_s_setprio(1);
        #pragma unroll
        for (int ni = 0; ni < 3; ++ni)
            #pragma unroll
            for (int m = 0; m < 4; ++m)
                acc[m][ni + 4] = __builtin_amdgcn_mfma_f32_16x16x32_bf16(a1[m], bD[ni], acc[m][ni + 4], 0, 0, 0);
        __builtin_amdgcn_s_setprio(0);
        asm volatile("s_waitcnt vmcnt(0)" ::: "memory");   // ks+1 loads landed
        __builtin_amdgcn_sched_barrier(0);
        __builtin_amdgcn_s_barrier();                      // all waves' loads landed
    }

    // epilogue: D row=(lane>>4)*4+r, col=lane&15
    #pragma unroll
    for (int m = 0; m < 4; ++m) {
        int row = m0 + wm * 64 + m * 16 + rq * 4;
        #pragma unroll
        for (int ni = 0; ni < 7; ++ni) {
            int n = n0 + wn * 112 + ni * 16 + r15;
            int b2 = n / 784, s2 = n - b2 * 784;
            float* op = out + ((size_t)b2 * CH + row) * 784 + s2;
            f32x4 v = acc[m][ni];
            #pragma unroll
            for (int r = 0; r < 4; ++r)
                op[(size_t)r * 784] = v[r] + bias[row + r];
        }
    }
}

extern "C" void kernel_launch(void* const* d_in, const int* in_sizes, int n_in,
                              void* d_out, int out_size, void* d_ws, size_t ws_size,
                              hipStream_t stream)
{
    const float* x    = (const float*)d_in[0];
    const float* wgt  = (const float*)d_in[1];
    const float* bias = (const float*)d_in[2];
    const float* mw   = (const float*)d_in[3];
    const float* filt = (const float*)d_in[4];

    const size_t XR_BYTES = (size_t)NB * HP * HP * CH * 2;   // 29,491,200
    const size_t WR_BYTES = (size_t)CH * KTOT * 2;           //  4,718,592
    u16* xr_pad = (u16*)d_ws;
    u16* w_r    = (u16*)((char*)d_ws + XR_BYTES);
    float* muX  = (float*)((char*)d_ws + XR_BYTES + WR_BYTES);
    float* muY  = (float*)((char*)d_ws + XR_BYTES + WR_BYTES + 65536);

    hipMemsetAsync(xr_pad, 0, XR_BYTES, stream);
    hipLaunchKernelGGL(stats_kernel, dim3(4096), dim3(256), 0, stream, x, muX, muY);
    hipLaunchKernelGGL(mask_relu_transpose, dim3(NB * 28), dim3(256), 0, stream,
                       x, mw, filt, muX, muY, xr_pad);
    hipLaunchKernelGGL(weight_reorder, dim3(512), dim3(256), 0, stream, wgt, w_r);
    hipLaunchKernelGGL(conv_gemm, dim3(224), dim3(512), 0, stream,
                       w_r, xr_pad, bias, (float*)d_out);
}